// Round 10
// baseline (87.348 us; speedup 1.0000x reference)
//
#include <hip/hip_runtime.h>
#include <math.h>

#define CROP 96
#define WIN 11
#define OUT 86          // CROP - WIN + 1
#define IMH 1080
#define IMW 1920
#define NRB 43          // out-rows per block: each (s,c) is split into 2 blocks
#define NCHK 6          // chunks of 8 out-rows (last chunk: 3 valid)
#define RSV 396         // words per row-slot: 12 x-blocks * (8*4 + 1 pad) = 33
#define NSLOT 16        // out-row slot ring (2 chunks: compute / prefetch)

typedef float v2f __attribute__((ext_vector_type(2)));

// vbuf[slot][x-block][8 float4 + pad]: per (out-row slot, col x) one float4
// (P, Q, PP, QQ) = VERTICAL 11-tap conv of p=a+b, q=a-b, p^2, q^2.
// word(slot,x) = slot*RSV + (x>>3)*33 + (x&7)*4  -> <=2-way banks both phases.
//
// Phase A (lanes 0..95): one column each, vertical conv of 8 out-rows from
// GLOBAL (lanes = consecutive cols -> coalesced: ~5 lines/instr vs ~44 for the
// old horizontal-first layout = the R6 transaction wall).
// Phase B (lanes 128..191): horizontal conv + SSIM, 12 out-cols per task,
// 22 ds_read_b128 per task (1.83/px).

__global__ __launch_bounds__(192) void ssim_kernel(
    const float* __restrict__ img,
    const float* __restrict__ imgr,
    const int* __restrict__ target,
    float* __restrict__ block_sums,
    unsigned int* __restrict__ counter,
    float* __restrict__ out,
    int nblk,
    float inv_npix)
{
    __shared__ __align__(16) float vbuf[NSLOT * RSV];   // 25344 B
    __shared__ float red[256];
    __shared__ unsigned int isLast;

    const int blk  = blockIdx.x;         // 0 .. 6N-1
    const int unit = blk >> 1;           // (s,c)
    const int hh   = blk & 1;            // row-half
    const int s    = unit / 3;
    const int c    = unit % 3;
    const int R0   = hh * NRB;           // first out-row of this block

    const int xmin = target[s * 5 + 0];
    const int ymin = target[s * 5 + 1];

    const size_t cbase = (size_t)c * (IMH * IMW) + (size_t)ymin * IMW + (size_t)xmin;
    const float* __restrict__ pa = img  + cbase;
    const float* __restrict__ pb = imgr + cbase;

    const int tid = threadIdx.x;

    // gaussian weights (f32, matches reference)
    float gw[WIN];
    {
        float sum = 0.f;
        #pragma unroll
        for (int k = 0; k < WIN; ++k) {
            const float cc = (float)k - (float)(WIN - 1) * 0.5f;
            gw[k] = expf(-(cc * cc) / (2.0f * 1.5f * 1.5f));
            sum += gw[k];
        }
        const float inv = 1.0f / sum;
        #pragma unroll
        for (int k = 0; k < WIN; ++k) gw[k] *= inv;
    }

    // ---- phase A: vertical 11-tap conv, col x = tid, 8 out-rows of chunk cc ----
    auto doA = [&](int cc) {
        const int x   = tid;             // 0..95
        const int brl = 8 * cc;          // local out-row base
        const int brg = R0 + brl;        // global out-row base
        v2f mPQ[8] = {}; v2f mP2[8] = {};
        #pragma unroll
        for (int tt = 0; tt < 18; ++tt) {     // input rows brg..brg+17 (clamped)
            int rg = brg + tt;
            rg = rg > (CROP - 1) ? (CROP - 1) : rg;   // only feeds unread rows
            const float a = pa[(size_t)rg * IMW + x];
            const float b = pb[(size_t)rg * IMW + x];
            const v2f pq  = {a + b, a - b};
            const v2f pq2 = pq * pq;
            #pragma unroll
            for (int jj = 0; jj < 8; ++jj) {
                const int kk = tt - jj;
                if (kk >= 0 && kk < WIN) {
                    mPQ[jj] += pq  * gw[kk];          // v_pk_fma_f32
                    mP2[jj] += pq2 * gw[kk];
                }
            }
        }
        const int xw = (x >> 3) * 33 + (x & 7) * 4;
        #pragma unroll
        for (int jj = 0; jj < 8; ++jj) {
            const int slot = (brl + jj) & (NSLOT - 1);
            *(float4*)&vbuf[slot * RSV + xw] =
                make_float4(mPQ[jj].x, mPQ[jj].y, mP2[jj].x, mP2[jj].y);
        }
    };

    // ---- phase B task coords (lanes 128..191) ----
    const int bt   = tid - 128;          // 0..63
    const int brow = bt >> 3;            // 0..7 local row within chunk
    const int bg   = bt & 7;             // col group
    const int x0   = (bg == 7) ? 84 : 12 * bg;   // g=7: 2 valid px (84,85)

    const float C1 = 6.5025f;
    const float C2 = 58.5225f;

    auto doB = [&](int cc, float& acc) {
        const int rl = 8 * cc + brow;    // local out-row
        if (rl >= NRB) return;           // tail chunk mask (global row = R0+rl < 86)
        const int sb = (rl & (NSLOT - 1)) * RSV;

        v2f aPQ[12] = {}; v2f aP2[12] = {};
        #pragma unroll
        for (int k = 0; k < 22; ++k) {   // window x0..x0+21 (clamped for g=7)
            int x = x0 + k;
            x = x > (CROP - 1) ? (CROP - 1) : x;      // clamped reads feed only masked px
            const int w = sb + (x >> 3) * 33 + (x & 7) * 4;
            const float4 f = *(const float4*)&vbuf[w];
            const v2f fPQ = {f.x, f.y};
            const v2f fP2 = {f.z, f.w};
            #pragma unroll
            for (int jj = 0; jj < 12; ++jj) {
                const int kk = k - jj;
                if (kk >= 0 && kk < WIN) {
                    aPQ[jj] += fPQ * gw[kk];          // v_pk_fma_f32
                    aP2[jj] += fP2 * gw[kk];
                }
            }
        }
        #pragma unroll
        for (int jj = 0; jj < 12; ++jj) {
            if (x0 + jj < OUT) {         // exact-once accumulate per out-px
                const v2f sq = aPQ[jj] * aPQ[jj];             // {P^2, Q^2}
                const float mu12x2  = (sq.x - sq.y) * 0.5f;          // 2*mu1*mu2
                const float musqsum = (sq.x + sq.y) * 0.5f;          // mu1^2+mu2^2
                const float e_dif = (aP2[jj].x - aP2[jj].y) * 0.5f;  // 2*E[ab]
                const float e_sum = (aP2[jj].x + aP2[jj].y) * 0.5f;  // E[a^2]+E[b^2]
                const float s12x2 = e_dif - mu12x2;
                const float ssum  = e_sum - musqsum;
                const float num = (mu12x2 + C1) * (s12x2 + C2);
                const float den = (musqsum + C1) * (ssum + C2);
                acc += num * __builtin_amdgcn_rcpf(den);
            }
        }
    };

    // ---- pipelined main loop: A(cc+1) || B(cc), one barrier per chunk ----
    if (tid < 96) doA(0);
    __syncthreads();

    float acc = 0.f;
    for (int cc = 0; cc < NCHK; ++cc) {
        if (cc + 1 < NCHK && tid < 96) doA(cc + 1);   // prefetch next chunk slots
        if (tid >= 128) doB(cc, acc);                 // consume current chunk
        __syncthreads();                              // orders A(cc+1) before B(cc+1)
    }

    // ---- deterministic block reduction (192 threads, padded to 256) ----
    red[tid] = acc;
    if (tid < 64) red[192 + tid] = 0.f;
    __syncthreads();
    #pragma unroll
    for (int off = 128; off > 0; off >>= 1) {
        if (tid < off) red[tid] += red[tid + off];
        __syncthreads();
    }

    // ---- fused finalize: last-arriving block reduces all block sums ----
    // Ticket pattern (no spinning -> safe under any dispatch order); fixed
    // reduction order -> bit-deterministic across replays.
    if (tid == 0) {
        block_sums[blk] = red[0];
        __threadfence();                 // release
        const unsigned int t = atomicAdd(counter, 1u);
        isLast = (t == (unsigned int)(nblk - 1)) ? 1u : 0u;
    }
    __syncthreads();
    if (isLast) {
        __threadfence();                 // acquire
        float ssum = 0.f;
        for (int i = tid; i < nblk; i += 192) ssum += block_sums[i];
        red[tid] = ssum;
        if (tid < 64) red[192 + tid] = 0.f;
        __syncthreads();
        #pragma unroll
        for (int off = 128; off > 0; off >>= 1) {
            if (tid < off) red[tid] += red[tid + off];
            __syncthreads();
        }
        if (tid == 0) out[0] = 5.0f * (1.0f - red[0] * inv_npix);
    }
}

extern "C" void kernel_launch(void* const* d_in, const int* in_sizes, int n_in,
                              void* d_out, int out_size, void* d_ws, size_t ws_size,
                              hipStream_t stream)
{
    const float* img  = (const float*)d_in[0];
    const float* imgr = (const float*)d_in[1];
    const int*   tgt  = (const int*)d_in[2];
    const int N = in_sizes[2] / 5;
    const int nblk = 6 * N;              // 2 row-halves x 3 channels x N

    float*        block_sums = (float*)d_ws;
    unsigned int* counter    = (unsigned int*)((float*)d_ws + nblk);

    const float inv_npix = 1.0f / ((float)(3 * N) * (float)(OUT * OUT));

    hipMemsetAsync((void*)counter, 0, sizeof(unsigned int), stream);
    ssim_kernel<<<nblk, 192, 0, stream>>>(img, imgr, tgt, block_sums, counter,
                                          (float*)d_out, nblk, inv_npix);
}

// Round 11
// 65.421 us; speedup vs baseline: 1.3352x; 1.3352x over previous
//
#include <hip/hip_runtime.h>
#include <math.h>

#define CROP 96
#define WIN 11
#define OUT 86          // CROP - WIN + 1
#define IMH 1080
#define IMW 1920
#define NIT 11          // chunks of 8 output rows: 86 = 10*8 + 6
#define RSW 356         // hbuf words per row-slot: 88*4 + pad -> 4 mod 32
#define NSLOT 32        // hbuf circular row buffer (input-row indexed)
#define PRS 202         // praw words per row: 2 imgs * 101 (101 pad -> bank spread)

typedef float v2f __attribute__((ext_vector_type(2)));

// hbuf[slot][x 0..87][4] = (P,Q,PP,QQ): horizontal 11-tap conv of p=a+b,
// q=a-b, p^2, q^2 for input row `slot`.
// praw[r][img][101]: raw pixels of 8 staged input rows, cols base4..base4+99
// (base4 = min(xmin&~3, IMW-100), block-uniform; window offset rr = xmin-base4).
//
// Per chunk: (1) ALL threads coalesced-stage next 8 input rows global->praw
// (400 float4, ~100 cache lines vs ~2200 for the old per-lane scalar loads =
// the R6 L1-transaction wall). (2) barrier. (3) wave3: hconv praw->hbuf;
// waves0-2: vertical conv + SSIM from hbuf. (4) barrier.

__global__ __launch_bounds__(256) void ssim_kernel(
    const float* __restrict__ img,
    const float* __restrict__ imgr,
    const int* __restrict__ target,
    float* __restrict__ block_sums,
    unsigned int* __restrict__ counter,
    float* __restrict__ out,
    int nblk,
    float inv_npix)
{
    __shared__ __align__(16) float hbuf[NSLOT * RSW];   // 45568 B
    __shared__ __align__(16) float praw[8 * PRS];       //  6464 B
    __shared__ float red[256];
    __shared__ unsigned int isLast;

    const int blk = blockIdx.x;          // 0 .. 3N-1
    const int s   = blk / 3;
    const int c   = blk % 3;

    const int xmin = target[s * 5 + 0];
    const int ymin = target[s * 5 + 1];

    int base4 = xmin & ~3;               // 16B-aligned window origin
    if (base4 > IMW - 100) base4 = IMW - 100;   // keep 100-col load in-row
    const int rr = xmin - base4;         // 0..4 block-uniform shift

    const size_t cbase = (size_t)c * (IMH * IMW) + (size_t)ymin * IMW + (size_t)base4;
    const float* __restrict__ pa = img  + cbase;
    const float* __restrict__ pb = imgr + cbase;

    const int tid  = threadIdx.x;
    const int wave = tid >> 6;
    const int lane = tid & 63;
    const int rot  = (blk ^ (blk >> 2) ^ (blk >> 5)) & 3;
    const int vt   = (((wave + rot) & 3) << 6) | lane;   // rotated roles

    // gaussian weights (f32, matches reference)
    float gw[WIN];
    {
        float sum = 0.f;
        #pragma unroll
        for (int k = 0; k < WIN; ++k) {
            const float cc = (float)k - (float)(WIN - 1) * 0.5f;
            gw[k] = expf(-(cc * cc) / (2.0f * 1.5f * 1.5f));
            sum += gw[k];
        }
        const float inv = 1.0f / sum;
        #pragma unroll
        for (int k = 0; k < WIN; ++k) gw[k] *= inv;
    }

    // ---- coalesced stage: nr input rows [firstRow..) -> praw (all threads) ----
    auto stage = [&](int firstRow, int nr) {
        const int total = nr * 50;               // float4 count (2 imgs * 25)
        for (int t = tid; t < total; t += 256) {
            const int row = t / 50;
            const int rem = t - row * 50;
            const int im  = rem / 25;
            const int c4  = rem - im * 25;
            const float* src = (im ? pb : pa) + (size_t)(firstRow + row) * IMW + 4 * c4;
            const float4 v = *(const float4*)src;
            *(float4*)&praw[row * PRS + im * 101 + 4 * c4] = v;
        }
    };

    // ---- horizontal 11-tap conv of praw row r (global row grow), 12 out-cols ----
    auto hconv = [&](int r, int grow, int g) {
        const int xo = (g == 7) ? 74 : 12 * g;   // out-cols xo..xo+11
        const int wb = r * PRS + rr + xo;
        v2f aPQ[12] = {}; v2f aP2[12] = {};
        #pragma unroll
        for (int tt = 0; tt < 22; ++tt) {
            const float a = praw[wb + tt];
            const float b = praw[wb + 101 + tt];
            const v2f pq  = {a + b, a - b};
            const v2f pq2 = pq * pq;
            #pragma unroll
            for (int jj = 0; jj < 12; ++jj) {
                const int kk = tt - jj;
                if (kk >= 0 && kk < WIN) {
                    aPQ[jj] += pq  * gw[kk];     // v_pk_fma_f32
                    aP2[jj] += pq2 * gw[kk];
                }
            }
        }
        const int sbase = (grow & (NSLOT - 1)) * RSW;
        #pragma unroll
        for (int jj = 0; jj < 12; ++jj) {
            const int x = xo + jj;               // g=7 overlaps g=6: bit-identical
            *(float4*)&hbuf[sbase + x * 4] =
                make_float4(aPQ[jj].x, aPQ[jj].y, aP2[jj].x, aP2[jj].y);
        }
    };

    // ---- prologue: input rows 0..17 in 3 stage+hconv rounds ----
    #pragma unroll
    for (int p = 0; p < 3; ++p) {
        const int fr = 8 * p;
        const int nr = (p == 2) ? 2 : 8;
        stage(fr, nr);
        __syncthreads();
        if (vt >= 192) {
            const int au = vt - 192;
            const int r  = au >> 3;
            if (r < nr) hconv(r, fr + r, au & 7);
        }
        __syncthreads();
    }

    const float C1 = 6.5025f;
    const float C2 = 58.5225f;
    float acc = 0.f;

    // hoisted task coordinates
    const int bx   = (vt < 172) ? (vt % 86) : 0;   // B: out-col
    const int bgrp = (vt < 172) ? (vt / 86) : 0;   // B: 4-row group 0/1
    const int au   = vt - 192;                     // A: 0..63 when vt>=192
    const int hr   = au >> 3;
    const int hg   = au & 7;

    for (int k = 0; k < NIT; ++k) {
        // ---- phase 1: coalesced stage of input rows 8k+18..8k+25 ----
        const int fr = 8 * k + 18;
        int nr = CROP - fr;                        // k=9: 6; k=10: <0
        nr = nr > 8 ? 8 : nr;
        if (nr > 0) stage(fr, nr);
        __syncthreads();

        // ---- phase 2: B (waves 0-2) || hconv (wave 3) ----
        if (vt < 172) {
            const int r0 = 8 * k + bgrp * 4;
            v2f mPQ[4] = {}; v2f mP2[4] = {};
            #pragma unroll
            for (int tt = 0; tt < 14; ++tt) {      // input rows r0..r0+13
                const int slot = (r0 + tt) & (NSLOT - 1);
                const float4 f = *(const float4*)&hbuf[slot * RSW + bx * 4];
                const v2f fPQ = {f.x, f.y};
                const v2f fP2 = {f.z, f.w};
                #pragma unroll
                for (int jj = 0; jj < 4; ++jj) {
                    const int kk = tt - jj;
                    if (kk >= 0 && kk < WIN) {
                        mPQ[jj] += fPQ * gw[kk];   // v_pk_fma_f32
                        mP2[jj] += fP2 * gw[kk];
                    }
                }
            }
            #pragma unroll
            for (int jj = 0; jj < 4; ++jj) {
                if (r0 + jj < OUT) {
                    const v2f sq = mPQ[jj] * mPQ[jj];            // {P^2, Q^2}
                    const float mu12x2  = (sq.x - sq.y) * 0.5f;         // 2*mu1*mu2
                    const float musqsum = (sq.x + sq.y) * 0.5f;         // mu1^2+mu2^2
                    const float e_dif = (mP2[jj].x - mP2[jj].y) * 0.5f; // 2*E[ab]
                    const float e_sum = (mP2[jj].x + mP2[jj].y) * 0.5f; // E[a^2]+E[b^2]
                    const float s12x2 = e_dif - mu12x2;
                    const float ssum  = e_sum - musqsum;
                    const float num = (mu12x2 + C1) * (s12x2 + C2);
                    const float den = (musqsum + C1) * (ssum + C2);
                    acc += num * __builtin_amdgcn_rcpf(den);
                }
            }
        } else if (vt >= 192) {
            if (hr < nr) hconv(hr, fr + hr, hg);
        }
        __syncthreads();
    }

    // ---- deterministic block reduction ----
    red[tid] = acc;
    __syncthreads();
    #pragma unroll
    for (int off = 128; off > 0; off >>= 1) {
        if (tid < off) red[tid] += red[tid + off];
        __syncthreads();
    }

    // ---- fused finalize: last-arriving block reduces all block sums ----
    // Ticket pattern (no spinning -> safe under any dispatch order); fixed
    // reduction order -> bit-deterministic across replays.
    if (tid == 0) {
        block_sums[blk] = red[0];
        __threadfence();                           // release (device scope)
        const unsigned int t = atomicAdd(counter, 1u);
        isLast = (t == (unsigned int)(nblk - 1)) ? 1u : 0u;
    }
    __syncthreads();
    if (isLast) {
        __threadfence();                           // acquire (device scope)
        float ssum = 0.f;
        for (int i = tid; i < nblk; i += 256) ssum += block_sums[i];
        red[tid] = ssum;
        __syncthreads();
        #pragma unroll
        for (int off = 128; off > 0; off >>= 1) {
            if (tid < off) red[tid] += red[tid + off];
            __syncthreads();
        }
        if (tid == 0) out[0] = 5.0f * (1.0f - red[0] * inv_npix);
    }
}

extern "C" void kernel_launch(void* const* d_in, const int* in_sizes, int n_in,
                              void* d_out, int out_size, void* d_ws, size_t ws_size,
                              hipStream_t stream)
{
    const float* img  = (const float*)d_in[0];
    const float* imgr = (const float*)d_in[1];
    const int*   tgt  = (const int*)d_in[2];
    const int N = in_sizes[2] / 5;
    const int nblk = 3 * N;

    float*        block_sums = (float*)d_ws;
    unsigned int* counter    = (unsigned int*)((float*)d_ws + nblk);

    const float inv_npix = 1.0f / ((float)nblk * (float)(OUT * OUT));

    hipMemsetAsync((void*)counter, 0, sizeof(unsigned int), stream);
    ssim_kernel<<<nblk, 256, 0, stream>>>(img, imgr, tgt, block_sums, counter,
                                          (float*)d_out, nblk, inv_npix);
}

// Round 12
// 61.730 us; speedup vs baseline: 1.4150x; 1.0598x over previous
//
#include <hip/hip_runtime.h>
#include <math.h>

#define CROP 96
#define WIN 11
#define OUT 86          // CROP - WIN + 1
#define IMH 1080
#define IMW 1920
#define NITER 14        // A active k<12 (input rows 8k..8k+7); B active k>=3 (out-chunk k-3)
#define RSW 356         // hbuf row-slot stride: ==4 mod 32 -> uniform b128 write banks
#define NSLOT 32        // hbuf input-row ring
#define PRW 101         // praw row stride: ==5 mod 32 -> 2-way scalar read banks

typedef float v2f __attribute__((ext_vector_type(2)));

// hbuf[slot][x 0..87][4] = (P,Q,PP,QQ): horizontal 11-tap conv of p=a+b,
// q=a-b, p^2, q^2 for input row `slot`.
// praw[im][r][PRW]: raw pixels of the A-wave's current 8 input rows
// (cols base4..base4+99; rr = xmin-base4 in [0,4], block-uniform).
//
// A-wave private pipeline (no extra barriers; praw touched ONLY by wave A):
//   iter k: issue 7 coalesced float4 loads (rows 8(k+1)..) -> regs
//           hconv rows 8k..8k+7 from praw -> hbuf
//           ds_write regs -> praw   (same-wave LDS order guarantees safety)
// This replaces R6's 44 scalar global loads/task (~44 cache lines per
// wave-instr = the TA wall) with ~126 fully-utilized lines per chunk.

__global__ __launch_bounds__(256) void ssim_kernel(
    const float* __restrict__ img,
    const float* __restrict__ imgr,
    const int* __restrict__ target,
    float* __restrict__ block_sums,
    unsigned int* __restrict__ counter,
    float* __restrict__ out,
    int nblk,
    float inv_npix)
{
    __shared__ __align__(16) float hbuf[NSLOT * RSW];   // 45568 B
    __shared__ __align__(16) float praw[2 * 8 * PRW];   //  6464 B
    __shared__ float red[256];
    __shared__ unsigned int isLast;

    const int blk = blockIdx.x;          // 0 .. 3N-1
    const int s   = blk / 3;
    const int c   = blk % 3;

    const int xmin = target[s * 5 + 0];
    const int ymin = target[s * 5 + 1];

    int base4 = xmin & ~3;               // 16B-aligned window origin
    if (base4 > IMW - 100) base4 = IMW - 100;   // keep 100-col window in-row
    const int rr = xmin - base4;         // 0..4 block-uniform shift

    const size_t cbase = (size_t)c * (IMH * IMW) + (size_t)ymin * IMW + (size_t)base4;
    const float* __restrict__ pa = img  + cbase;
    const float* __restrict__ pb = imgr + cbase;

    const int tid  = threadIdx.x;
    const int wave = tid >> 6;
    const int lane = tid & 63;
    const int rot  = (blk >> 8) & 3;     // co-resident blocks are blk+256j
    const int vt   = (((wave + rot) & 3) << 6) | lane;

    // gaussian weights (f32, matches reference)
    float gw[WIN];
    {
        float sum = 0.f;
        #pragma unroll
        for (int k = 0; k < WIN; ++k) {
            const float cc = (float)k - (float)(WIN - 1) * 0.5f;
            gw[k] = expf(-(cc * cc) / (2.0f * 1.5f * 1.5f));
            sum += gw[k];
        }
        const float inv = 1.0f / sum;
        #pragma unroll
        for (int k = 0; k < WIN; ++k) gw[k] *= inv;
    }

    const bool isA = (vt >= 192);
    const int  au  = vt - 192;           // 0..63 for the A-wave
    const int  hr  = au >> 3;            // hconv row 0..7
    const int  hg  = au & 7;             // hconv col group
    const int  bx   = (vt < 172) ? (vt % 86) : 0;   // B: out-col
    const int  bgrp = (vt < 172) ? (vt / 86) : 0;   // B: 4-row group

    // ---- A: issue coalesced loads of 8 input rows [row0..row0+8) ----
    float4 vv[7]; int wadr[7];
    auto issueLoads = [&](int row0) {
        #pragma unroll
        for (int j = 0; j < 7; ++j) {
            const int t = au + 64 * j;   // 400 float4: 2 img x 8 rows x 25
            if (t < 400) {
                const int im  = t / 200;
                const int rem = t - im * 200;
                const int r2  = rem / 25;
                const int c4  = rem - r2 * 25;
                vv[j] = *(const float4*)((im ? pb : pa)
                        + (size_t)(row0 + r2) * IMW + 4 * c4);
                wadr[j] = im * (8 * PRW) + r2 * PRW + 4 * c4;
            }
        }
    };
    auto writePraw = [&]() {
        #pragma unroll
        for (int j = 0; j < 7; ++j) {
            const int t = au + 64 * j;
            if (t < 400) {               // b32 writes: conflict-free, no align trap
                praw[wadr[j] + 0] = vv[j].x;
                praw[wadr[j] + 1] = vv[j].y;
                praw[wadr[j] + 2] = vv[j].z;
                praw[wadr[j] + 3] = vv[j].w;
            }
        }
    };

    // ---- A: horizontal 11-tap conv of praw row hr (global row grow) ----
    auto hconv = [&](int grow) {
        const int xo = (hg == 7) ? 74 : 12 * hg;   // out-cols xo..xo+11
        const int wb = hr * PRW + rr + xo;
        v2f aPQ[12] = {}; v2f aP2[12] = {};
        #pragma unroll
        for (int tt = 0; tt < 22; ++tt) {
            const float a = praw[wb + tt];
            const float b = praw[wb + 8 * PRW + tt];
            const v2f pq  = {a + b, a - b};
            const v2f pq2 = pq * pq;
            #pragma unroll
            for (int jj = 0; jj < 12; ++jj) {
                const int kk = tt - jj;
                if (kk >= 0 && kk < WIN) {
                    aPQ[jj] += pq  * gw[kk];       // v_pk_fma_f32
                    aP2[jj] += pq2 * gw[kk];
                }
            }
        }
        const int sbase = (grow & (NSLOT - 1)) * RSW;
        #pragma unroll
        for (int jj = 0; jj < 12; ++jj) {
            const int x = xo + jj;                 // g=7 overlaps g=6: bit-identical
            *(float4*)&hbuf[sbase + x * 4] =
                make_float4(aPQ[jj].x, aPQ[jj].y, aP2[jj].x, aP2[jj].y);
        }
    };

    // ---- prologue: A-wave fills praw with rows 0..7 (wave-private, no barrier) ----
    if (isA) { issueLoads(0); writePraw(); }

    const float C1 = 6.5025f;
    const float C2 = 58.5225f;
    float acc = 0.f;

    for (int k = 0; k < NITER; ++k) {
        if (isA) {
            if (k < 12) {
                if (k + 1 < 12) issueLoads(8 * (k + 1));   // latency hides under hconv
                hconv(8 * k + hr);                         // reads praw (current rows)
                if (k + 1 < 12) writePraw();               // same-wave order: safe
            }
        } else if (vt < 172 && k >= 3) {
            // ---- B: vertical 11-tap conv + SSIM, 4 out-rows x 1 col ----
            const int q  = k - 3;
            const int r0 = 8 * q + 4 * bgrp;
            v2f mPQ[4] = {}; v2f mP2[4] = {};
            #pragma unroll
            for (int tt = 0; tt < 14; ++tt) {      // input rows r0..r0+13
                const int slot = (r0 + tt) & (NSLOT - 1);
                const float4 f = *(const float4*)&hbuf[slot * RSW + bx * 4];
                const v2f fPQ = {f.x, f.y};
                const v2f fP2 = {f.z, f.w};
                #pragma unroll
                for (int jj = 0; jj < 4; ++jj) {
                    const int kk = tt - jj;
                    if (kk >= 0 && kk < WIN) {
                        mPQ[jj] += fPQ * gw[kk];   // v_pk_fma_f32
                        mP2[jj] += fP2 * gw[kk];
                    }
                }
            }
            #pragma unroll
            for (int jj = 0; jj < 4; ++jj) {
                if (r0 + jj < OUT) {
                    const v2f sq = mPQ[jj] * mPQ[jj];            // {P^2, Q^2}
                    const float mu12x2  = (sq.x - sq.y) * 0.5f;         // 2*mu1*mu2
                    const float musqsum = (sq.x + sq.y) * 0.5f;         // mu1^2+mu2^2
                    const float e_dif = (mP2[jj].x - mP2[jj].y) * 0.5f; // 2*E[ab]
                    const float e_sum = (mP2[jj].x + mP2[jj].y) * 0.5f; // E[a^2]+E[b^2]
                    const float s12x2 = e_dif - mu12x2;
                    const float ssum  = e_sum - musqsum;
                    const float num = (mu12x2 + C1) * (s12x2 + C2);
                    const float den = (musqsum + C1) * (ssum + C2);
                    acc += num * __builtin_amdgcn_rcpf(den);
                }
            }
        }
        __syncthreads();   // orders hconv(k) writes before B reads at k+1..
    }

    // ---- deterministic block reduction ----
    red[tid] = acc;
    __syncthreads();
    #pragma unroll
    for (int off = 128; off > 0; off >>= 1) {
        if (tid < off) red[tid] += red[tid + off];
        __syncthreads();
    }

    // ---- fused finalize: last-arriving block reduces all block sums ----
    // Ticket pattern (no spinning -> safe under any dispatch order); fixed
    // reduction order -> bit-deterministic across replays.
    if (tid == 0) {
        block_sums[blk] = red[0];
        __threadfence();                           // release (device scope)
        const unsigned int t = atomicAdd(counter, 1u);
        isLast = (t == (unsigned int)(nblk - 1)) ? 1u : 0u;
    }
    __syncthreads();
    if (isLast) {
        __threadfence();                           // acquire (device scope)
        float ssum = 0.f;
        for (int i = tid; i < nblk; i += 256) ssum += block_sums[i];
        red[tid] = ssum;
        __syncthreads();
        #pragma unroll
        for (int off = 128; off > 0; off >>= 1) {
            if (tid < off) red[tid] += red[tid + off];
            __syncthreads();
        }
        if (tid == 0) out[0] = 5.0f * (1.0f - red[0] * inv_npix);
    }
}

extern "C" void kernel_launch(void* const* d_in, const int* in_sizes, int n_in,
                              void* d_out, int out_size, void* d_ws, size_t ws_size,
                              hipStream_t stream)
{
    const float* img  = (const float*)d_in[0];
    const float* imgr = (const float*)d_in[1];
    const int*   tgt  = (const int*)d_in[2];
    const int N = in_sizes[2] / 5;
    const int nblk = 3 * N;

    float*        block_sums = (float*)d_ws;
    unsigned int* counter    = (unsigned int*)((float*)d_ws + nblk);

    const float inv_npix = 1.0f / ((float)nblk * (float)(OUT * OUT));

    hipMemsetAsync((void*)counter, 0, sizeof(unsigned int), stream);
    ssim_kernel<<<nblk, 256, 0, stream>>>(img, imgr, tgt, block_sums, counter,
                                          (float*)d_out, nblk, inv_npix);
}

// Round 13
// 54.476 us; speedup vs baseline: 1.6034x; 1.1332x over previous
//
#include <hip/hip_runtime.h>
#include <math.h>

#define CROP 96
#define WIN 11
#define OUT 86          // CROP - WIN + 1
#define IMH 1080
#define IMW 1920
#define NIT 11          // chunks of 8 output rows: 86 = 10*8 + 6
#define RSW 348         // hbuf row-slot stride: 86*4 + 4 pad -> 28 mod 32 (bank-rotating)
#define NSLOT 24        // ring slots: B reads 14 + A writes 8 = 22 live; 24 = margin

typedef float v2f __attribute__((ext_vector_type(2)));

// hbuf[slot][x 0..85][4] = (P,Q,PP,QQ): horizontal 11-tap conv of p=a+b,
// q=a-b, p^2, q^2 for input row `slot` (slot = row % 24).
//
// R6 champion structure; LDS shrunk 45.5->33.4 KB so 4 blocks (16 waves)
// fit per CU instead of 3 (12) -- the kernel is stall-bound (~15% per-wave
// issue duty), so resident-wave count is the first-order lever.

__global__ __launch_bounds__(256) void ssim_kernel(
    const float* __restrict__ img,
    const float* __restrict__ imgr,
    const int* __restrict__ target,
    float* __restrict__ block_sums,
    unsigned int* __restrict__ counter,
    float* __restrict__ out,
    int nblk,
    float inv_npix)
{
    __shared__ __align__(16) float hbuf[NSLOT * RSW];   // 33408 B
    __shared__ float red[256];
    __shared__ unsigned int isLast;

    const int blk = blockIdx.x;          // 0 .. 3N-1
    const int s   = blk / 3;
    const int c   = blk % 3;

    const int xmin = target[s * 5 + 0];
    const int ymin = target[s * 5 + 1];

    const size_t cbase = (size_t)c * (IMH * IMW) + (size_t)ymin * IMW + (size_t)xmin;
    const float* __restrict__ pa = img  + cbase;
    const float* __restrict__ pb = imgr + cbase;

    const int tid = threadIdx.x;

    // gaussian weights (f32, matches reference)
    float gw[WIN];
    {
        float sum = 0.f;
        #pragma unroll
        for (int k = 0; k < WIN; ++k) {
            const float cc = (float)k - (float)(WIN - 1) * 0.5f;
            gw[k] = expf(-(cc * cc) / (2.0f * 1.5f * 1.5f));
            sum += gw[k];
        }
        const float inv = 1.0f / sum;
        #pragma unroll
        for (int k = 0; k < WIN; ++k) gw[k] *= inv;
    }

    // ---- horizontal 11-tap conv of one input row, 12 out-cols, packed pairs ----
    auto doA_task = [&](int row, int g) {
        const int xo = (g == 7) ? 74 : 12 * g;         // window xo..xo+21 <= 95
        const float* __restrict__ ra = pa + (size_t)row * IMW + xo;
        const float* __restrict__ rb = pb + (size_t)row * IMW + xo;

        v2f aPQ[12] = {}; v2f aP2[12] = {};
        #pragma unroll
        for (int tt = 0; tt < 22; ++tt) {              // static offsets, no clamp
            const float a = ra[tt];
            const float b = rb[tt];
            const v2f pq  = {a + b, a - b};
            const v2f pq2 = pq * pq;
            #pragma unroll
            for (int jj = 0; jj < 12; ++jj) {
                const int kk = tt - jj;
                if (kk >= 0 && kk < WIN) {
                    aPQ[jj] += pq  * gw[kk];           // v_pk_fma_f32
                    aP2[jj] += pq2 * gw[kk];
                }
            }
        }
        const int sbase = ((unsigned)row % (unsigned)NSLOT) * RSW;
        #pragma unroll
        for (int jj = 0; jj < 12; ++jj) {
            const int x = xo + jj;                     // g=7 overlaps g=6: bit-identical
            *(float4*)&hbuf[sbase + x * 4] =
                make_float4(aPQ[jj].x, aPQ[jj].y, aP2[jj].x, aP2[jj].y);
        }
    };

    // ---- prologue: fill input rows 0..17 (18 rows x 8 groups = 144 tasks) ----
    if (tid < 144) doA_task(tid >> 3, tid & 7);
    __syncthreads();

    const float C1 = 6.5025f;
    const float C2 = 58.5225f;
    float acc = 0.f;

    // hoisted per-thread task coordinates
    const int bx    = (tid < 172) ? (tid % 86) : 0;    // B: out-col
    const int bgrp  = (tid < 172) ? (tid / 86) : 0;    // B: 4-row group 0/1
    const int au    = tid - 192;                       // A: 0..63 when tid>=192
    const int arow0 = (au >> 3) + 18;
    const int ag    = au & 7;

    for (int k = 0; k < NIT; ++k) {
        const int r0out = 8 * k;

        if (tid < 172) {
            // ---- B: vertical 11-tap conv + SSIM, 4 out-rows x 1 col ----
            const int r0  = r0out + bgrp * 4;
            const int sl0 = (unsigned)r0 % (unsigned)NSLOT;
            v2f mPQ[4] = {}; v2f mP2[4] = {};
            #pragma unroll
            for (int tt = 0; tt < 14; ++tt) {          // input rows r0..r0+13
                int sl = sl0 + tt;                     // <= 23+13 = 36: wrap once
                if (sl >= NSLOT) sl -= NSLOT;
                const float4 f = *(const float4*)&hbuf[sl * RSW + bx * 4];
                const v2f fPQ = {f.x, f.y};
                const v2f fP2 = {f.z, f.w};
                #pragma unroll
                for (int jj = 0; jj < 4; ++jj) {
                    const int kk = tt - jj;
                    if (kk >= 0 && kk < WIN) {
                        mPQ[jj] += fPQ * gw[kk];       // v_pk_fma_f32
                        mP2[jj] += fP2 * gw[kk];
                    }
                }
            }
            #pragma unroll
            for (int jj = 0; jj < 4; ++jj) {
                if (r0 + jj < OUT) {
                    const v2f sq = mPQ[jj] * mPQ[jj];          // {P^2, Q^2}
                    const float mu12x2  = (sq.x - sq.y) * 0.5f;       // 2*mu1*mu2
                    const float musqsum = (sq.x + sq.y) * 0.5f;       // mu1^2+mu2^2
                    const float e_dif = (mP2[jj].x - mP2[jj].y) * 0.5f; // 2*E[ab]
                    const float e_sum = (mP2[jj].x + mP2[jj].y) * 0.5f; // E[a^2]+E[b^2]
                    const float s12x2 = e_dif - mu12x2;
                    const float ssum  = e_sum - musqsum;
                    const float num = (mu12x2 + C1) * (s12x2 + C2);
                    const float den = (musqsum + C1) * (ssum + C2);
                    acc += num * __builtin_amdgcn_rcpf(den);
                }
            }
        } else if (tid >= 192) {
            // ---- A: horizontal conv of next chunk's input rows ----
            const int row = r0out + arow0;             // 8k+18 .. 8k+25
            if (row < CROP) doA_task(row, ag);
        }
        __syncthreads();
    }

    // ---- deterministic block reduction ----
    red[tid] = acc;
    __syncthreads();
    #pragma unroll
    for (int off = 128; off > 0; off >>= 1) {
        if (tid < off) red[tid] += red[tid + off];
        __syncthreads();
    }

    // ---- fused finalize: last-arriving block reduces all block sums ----
    // Ticket pattern (no spinning -> safe under any dispatch order); fixed
    // reduction order -> bit-deterministic across replays.
    if (tid == 0) {
        block_sums[blk] = red[0];
        __threadfence();                               // release (device scope)
        const unsigned int t = atomicAdd(counter, 1u);
        isLast = (t == (unsigned int)(nblk - 1)) ? 1u : 0u;
    }
    __syncthreads();
    if (isLast) {
        __threadfence();                               // acquire (device scope)
        float ssum = 0.f;
        for (int i = tid; i < nblk; i += 256) ssum += block_sums[i];
        red[tid] = ssum;
        __syncthreads();
        #pragma unroll
        for (int off = 128; off > 0; off >>= 1) {
            if (tid < off) red[tid] += red[tid + off];
            __syncthreads();
        }
        if (tid == 0) out[0] = 5.0f * (1.0f - red[0] * inv_npix);
    }
}

extern "C" void kernel_launch(void* const* d_in, const int* in_sizes, int n_in,
                              void* d_out, int out_size, void* d_ws, size_t ws_size,
                              hipStream_t stream)
{
    const float* img  = (const float*)d_in[0];
    const float* imgr = (const float*)d_in[1];
    const int*   tgt  = (const int*)d_in[2];
    const int N = in_sizes[2] / 5;
    const int nblk = 3 * N;

    float*        block_sums = (float*)d_ws;
    unsigned int* counter    = (unsigned int*)((float*)d_ws + nblk);

    const float inv_npix = 1.0f / ((float)nblk * (float)(OUT * OUT));

    hipMemsetAsync((void*)counter, 0, sizeof(unsigned int), stream);
    ssim_kernel<<<nblk, 256, 0, stream>>>(img, imgr, tgt, block_sums, counter,
                                          (float*)d_out, nblk, inv_npix);
}

// Round 14
// 37.152 us; speedup vs baseline: 2.3511x; 1.4663x over previous
//
#include <hip/hip_runtime.h>
#include <math.h>

#define CROP 96
#define WIN 11
#define OUT 86          // CROP - WIN + 1
#define IMH 1080
#define IMW 1920
#define HOUT 43         // out-rows per block (2 row-halves per (s,c))
#define HIN 53          // input rows needed per half: 43 + WIN - 1
#define NIT 6           // chunks of 8 out-rows: 43 = 5*8 + 3
#define RSW 348         // hbuf row-slot stride: 86*4 + 4 pad -> 28 mod 32 (bank-rotating)
#define NSLOT 26        // ring slots; write-read row distance <= 25 < 26 -> no alias race

typedef float v2f __attribute__((ext_vector_type(2)));

// hbuf[slot][x 0..85][4] = (P,Q,PP,QQ): horizontal 11-tap conv of p=a+b,
// q=a-b, p^2, q^2 for LOCAL input row `slot` (slot = local_row % 26).
//
// R6 champion structure. Occupancy lever: 1536 blocks (2 row-halves per
// (s,c)) x 36.2KB LDS -> 4 blocks = 16 waves resident/CU (vs 768 blocks = 3
// blocks = 12 waves). Kernel is stall-bound (~42% VALUBusy @12 waves), so
// resident waves are first-order. NO device-scope fence/atomic finalize:
// __threadfence() emits L2 writeback/invalidate on gfx950 -- measured ~+20us
// across R9/R13 (both landed at ~54us with unrelated changes + ticket).

__global__ __launch_bounds__(256) void ssim_kernel(
    const float* __restrict__ img,
    const float* __restrict__ imgr,
    const int* __restrict__ target,
    float* __restrict__ block_sums)
{
    __shared__ __align__(16) float hbuf[NSLOT * RSW];   // 36192 B
    __shared__ float red[256];

    const int blk  = blockIdx.x;         // 0 .. 6N-1
    const int unit = blk >> 1;           // (s,c)
    const int hh   = blk & 1;            // row-half
    const int s    = unit / 3;
    const int c    = unit % 3;
    const int R0   = hh * HOUT;          // first out-row (global within crop)

    const int xmin = target[s * 5 + 0];
    const int ymin = target[s * 5 + 1];

    const size_t cbase = (size_t)c * (IMH * IMW)
                       + (size_t)(ymin + R0) * IMW + (size_t)xmin;
    const float* __restrict__ pa = img  + cbase;   // local row 0 = crop row R0
    const float* __restrict__ pb = imgr + cbase;

    const int tid = threadIdx.x;

    // gaussian weights (f32, matches reference)
    float gw[WIN];
    {
        float sum = 0.f;
        #pragma unroll
        for (int k = 0; k < WIN; ++k) {
            const float cc = (float)k - (float)(WIN - 1) * 0.5f;
            gw[k] = expf(-(cc * cc) / (2.0f * 1.5f * 1.5f));
            sum += gw[k];
        }
        const float inv = 1.0f / sum;
        #pragma unroll
        for (int k = 0; k < WIN; ++k) gw[k] *= inv;
    }

    // ---- A: horizontal 11-tap conv of one local input row, 12 out-cols ----
    auto doA_task = [&](int row, int g) {
        const int xo = (g == 7) ? 74 : 12 * g;         // window xo..xo+21 <= 95
        const float* __restrict__ ra = pa + (size_t)row * IMW + xo;
        const float* __restrict__ rb = pb + (size_t)row * IMW + xo;

        v2f aPQ[12] = {}; v2f aP2[12] = {};
        #pragma unroll
        for (int tt = 0; tt < 22; ++tt) {              // static offsets, no clamp
            const float a = ra[tt];
            const float b = rb[tt];
            const v2f pq  = {a + b, a - b};
            const v2f pq2 = pq * pq;
            #pragma unroll
            for (int jj = 0; jj < 12; ++jj) {
                const int kk = tt - jj;
                if (kk >= 0 && kk < WIN) {
                    aPQ[jj] += pq  * gw[kk];           // v_pk_fma_f32
                    aP2[jj] += pq2 * gw[kk];
                }
            }
        }
        const int sbase = ((unsigned)row % (unsigned)NSLOT) * RSW;
        #pragma unroll
        for (int jj = 0; jj < 12; ++jj) {
            const int x = xo + jj;                     // g=7 overlaps g=6: bit-identical
            *(float4*)&hbuf[sbase + x * 4] =
                make_float4(aPQ[jj].x, aPQ[jj].y, aP2[jj].x, aP2[jj].y);
        }
    };

    // ---- prologue: local input rows 0..17 (18 rows x 8 groups = 144 tasks) ----
    if (tid < 144) doA_task(tid >> 3, tid & 7);
    __syncthreads();

    const float C1 = 6.5025f;
    const float C2 = 58.5225f;
    float acc = 0.f;

    // hoisted per-thread task coordinates
    const int bx    = (tid < 172) ? (tid % 86) : 0;    // B: out-col
    const int bgrp  = (tid < 172) ? (tid / 86) : 0;    // B: 4-row group 0/1
    const int au    = tid - 192;                       // A: 0..63 when tid>=192
    const int arow0 = (au >> 3) + 18;
    const int ag    = au & 7;

    for (int k = 0; k < NIT; ++k) {
        const int r0out = 8 * k;

        if (tid < 172) {
            // ---- B: vertical 11-tap conv + SSIM, 4 local out-rows x 1 col ----
            const int r0  = r0out + bgrp * 4;
            const int sl0 = (unsigned)r0 % (unsigned)NSLOT;
            v2f mPQ[4] = {}; v2f mP2[4] = {};
            #pragma unroll
            for (int tt = 0; tt < 14; ++tt) {          // local input rows r0..r0+13
                int sl = sl0 + tt;                     // <= 25+13: wrap once
                if (sl >= NSLOT) sl -= NSLOT;
                const float4 f = *(const float4*)&hbuf[sl * RSW + bx * 4];
                const v2f fPQ = {f.x, f.y};
                const v2f fP2 = {f.z, f.w};
                #pragma unroll
                for (int jj = 0; jj < 4; ++jj) {
                    const int kk = tt - jj;
                    if (kk >= 0 && kk < WIN) {
                        mPQ[jj] += fPQ * gw[kk];       // v_pk_fma_f32
                        mP2[jj] += fP2 * gw[kk];
                    }
                }
            }
            #pragma unroll
            for (int jj = 0; jj < 4; ++jj) {
                if (r0 + jj < HOUT) {                  // local out-row mask
                    const v2f sq = mPQ[jj] * mPQ[jj];          // {P^2, Q^2}
                    const float mu12x2  = (sq.x - sq.y) * 0.5f;       // 2*mu1*mu2
                    const float musqsum = (sq.x + sq.y) * 0.5f;       // mu1^2+mu2^2
                    const float e_dif = (mP2[jj].x - mP2[jj].y) * 0.5f; // 2*E[ab]
                    const float e_sum = (mP2[jj].x + mP2[jj].y) * 0.5f; // E[a^2]+E[b^2]
                    const float s12x2 = e_dif - mu12x2;
                    const float ssum  = e_sum - musqsum;
                    const float num = (mu12x2 + C1) * (s12x2 + C2);
                    const float den = (musqsum + C1) * (ssum + C2);
                    acc += num * __builtin_amdgcn_rcpf(den);
                }
            }
        } else if (tid >= 192) {
            // ---- A: horizontal conv of next chunk's local input rows ----
            const int row = r0out + arow0;             // 8k+18 .. 8k+25
            if (row < HIN) doA_task(row, ag);
        }
        __syncthreads();
    }

    // ---- deterministic block reduction ----
    red[tid] = acc;
    __syncthreads();
    #pragma unroll
    for (int off = 128; off > 0; off >>= 1) {
        if (tid < off) red[tid] += red[tid + off];
        __syncthreads();
    }
    if (tid == 0) block_sums[blk] = red[0];
}

__global__ __launch_bounds__(256) void ssim_finalize_kernel(
    const float* __restrict__ block_sums,
    float* __restrict__ out,
    int nblk,
    float inv_npix)
{
    __shared__ float red[256];
    const int tid = threadIdx.x;
    float s = 0.f;
    for (int i = tid; i < nblk; i += 256) s += block_sums[i];
    red[tid] = s;
    __syncthreads();
    #pragma unroll
    for (int off = 128; off > 0; off >>= 1) {
        if (tid < off) red[tid] += red[tid + off];
        __syncthreads();
    }
    if (tid == 0) {
        const float mean = red[0] * inv_npix;
        out[0] = 5.0f * (1.0f - mean);
    }
}

extern "C" void kernel_launch(void* const* d_in, const int* in_sizes, int n_in,
                              void* d_out, int out_size, void* d_ws, size_t ws_size,
                              hipStream_t stream)
{
    const float* img  = (const float*)d_in[0];
    const float* imgr = (const float*)d_in[1];
    const int*   tgt  = (const int*)d_in[2];
    const int N = in_sizes[2] / 5;
    const int nblk = 6 * N;              // 2 row-halves x 3 channels x N

    float* block_sums = (float*)d_ws;
    const float inv_npix = 1.0f / ((float)(3 * N) * (float)(OUT * OUT));

    ssim_kernel<<<nblk, 256, 0, stream>>>(img, imgr, tgt, block_sums);
    ssim_finalize_kernel<<<1, 256, 0, stream>>>(block_sums, (float*)d_out, nblk, inv_npix);
}